// Round 3
// baseline (53.784 us; speedup 1.0000x reference)
//
#include <hip/hip_runtime.h>

#define VEC_D   128
#define N_WORDS 100000
#define BATCH   16384
#define CTX     8
#define NS      16

typedef float f32x4 __attribute__((ext_vector_type(4)));

// ---------------------------------------------------------------------------
// Kernel 1: transpose outputs [128, N_WORDS] -> outT [N_WORDS, 128]
// Tile = 32 words x 128 d. N_WORDS = 3125 * 32 exactly (no bounds checks).
// float4 reads along words (nontemporal: outputs is read exactly once, keep
// L3 free for outT), float4 writes along d.
// ---------------------------------------------------------------------------
__global__ __launch_bounds__(256) void transpose_kernel(
    const float* __restrict__ src,   // [128][N_WORDS]
    float* __restrict__ dst)         // [N_WORDS][128]
{
    __shared__ float lds[32][VEC_D + 1];  // [w][d], stride 129 -> write banks (w+d)%32
    const int tid = threadIdx.x;
    const int w0  = blockIdx.x * 32;

    // Read: 4 passes, 32 d-rows per pass, each lane reads a float4 of words.
    // LDS scatter: banks (4j+k+d)%32 -> 2-way at worst (free).
    #pragma unroll
    for (int p = 0; p < 4; ++p) {
        const int d = p * 32 + (tid >> 3);
        const int w = (tid & 7) * 4;
        const f32x4 v = __builtin_nontemporal_load(
            (const f32x4*)&src[(size_t)d * N_WORDS + w0 + w]);
        lds[w + 0][d] = v.x;
        lds[w + 1][d] = v.y;
        lds[w + 2][d] = v.z;
        lds[w + 3][d] = v.w;
    }
    __syncthreads();

    // Write: 4 passes, 8 words per pass, each lane writes a float4 of d.
    // LDS row-contiguous float4 reads = standard optimal pattern.
    #pragma unroll
    for (int p = 0; p < 4; ++p) {
        const int wl = p * 8 + (tid >> 5);
        const int d4 = (tid & 31) * 4;
        f32x4 v;
        v.x = lds[wl][d4 + 0];
        v.y = lds[wl][d4 + 1];
        v.z = lds[wl][d4 + 2];
        v.w = lds[wl][d4 + 3];
        *(f32x4*)&dst[(size_t)(w0 + wl) * VEC_D + d4] = v;
    }
}

// ---------------------------------------------------------------------------
// Kernel 2: main compute. 16 lanes per batch row (quarter-wave); lane owns
// d = 8*l .. 8*l+7 (two float4s, 32 B in flight per gather). 9 row gathers
// build the input slice; 16 contiguous outT gathers give per-lane partials
// acc[0..15]; a single 4-step butterfly fold reduces all 16 dots in 15
// shuffles; lane l ends holding sample brev4(l).
// ---------------------------------------------------------------------------
template <bool TRANSPOSED>
__global__ __launch_bounds__(256) void dm_kernel(
    const int*   __restrict__ doc_ids,
    const int*   __restrict__ context_ids,
    const int*   __restrict__ sample_ids,
    const float* __restrict__ pm,      // [N_DOCS][128]
    const float* __restrict__ wm,      // [N_WORDS][128]
    const float* __restrict__ outsrc,  // TRANSPOSED ? outT [N_WORDS][128] : outputs [128][N_WORDS]
    float*       __restrict__ out)     // [BATCH][NS]
{
    const int tid = threadIdx.x;
    const int l   = tid & 15;                   // lane within quarter-wave
    const int b   = blockIdx.x * 16 + (tid >> 4);
    const int d0  = l * 8;

    // Build input vector slice: pm[doc] + sum_c wm[ctx[c]]
    const int doc = doc_ids[b];
    const f32x4* pr = (const f32x4*)&pm[(size_t)doc * VEC_D + d0];
    f32x4 v0 = pr[0], v1 = pr[1];
    #pragma unroll
    for (int c = 0; c < CTX; ++c) {
        const int wid = context_ids[b * CTX + c];
        const f32x4* wr = (const f32x4*)&wm[(size_t)wid * VEC_D + d0];
        v0 += wr[0];
        v1 += wr[1];
    }

    // Per-lane partial dot for each of the 16 samples.
    float acc[NS];
    #pragma unroll
    for (int s = 0; s < NS; ++s) {
        const int wid = sample_ids[b * NS + s];
        if (TRANSPOSED) {
            const f32x4* orow = (const f32x4*)&outsrc[(size_t)wid * VEC_D + d0];
            const f32x4 o0 = orow[0], o1 = orow[1];
            acc[s] = v0.x * o0.x + v0.y * o0.y + v0.z * o0.z + v0.w * o0.w
                   + v1.x * o1.x + v1.y * o1.y + v1.z * o1.z + v1.w * o1.w;
        } else {
            float a = 0.0f;
            #pragma unroll
            for (int k = 0; k < 4; ++k)
                a += v0[k] * outsrc[(size_t)(d0 + k) * N_WORDS + wid];
            #pragma unroll
            for (int k = 0; k < 4; ++k)
                a += v1[k] * outsrc[(size_t)(d0 + 4 + k) * N_WORDS + wid];
            acc[s] = a;
        }
    }

    // Butterfly fold: 16 lanes x 16 values -> 1 value/lane in 15 shuffles.
    // Step j (mask m=1<<j): lane with bit j == 0 accumulates the lower half
    // of the current index range, bit j == 1 the upper half.
    #pragma unroll
    for (int j = 0; j < 4; ++j) {
        const int m = 1 << j;
        const int h = 8 >> j;                    // half-length at this step
        const bool hi = (l & m) != 0;
        #pragma unroll
        for (int i = 0; i < h; ++i) {
            const float send = hi ? acc[i] : acc[h + i];
            const float recv = __shfl_xor(send, m, 64);
            acc[i] = (hi ? acc[h + i] : acc[i]) + recv;
        }
    }
    // lane l holds sample s = bit-reverse-4(l)
    const int s = ((l & 1) << 3) | ((l & 2) << 1) | ((l & 4) >> 1) | ((l & 8) >> 3);
    out[(size_t)b * NS + s] = acc[0];
}

extern "C" void kernel_launch(void* const* d_in, const int* in_sizes, int n_in,
                              void* d_out, int out_size, void* d_ws, size_t ws_size,
                              hipStream_t stream) {
    const int*   doc_ids     = (const int*)d_in[0];
    const int*   context_ids = (const int*)d_in[1];
    const int*   sample_ids  = (const int*)d_in[2];
    const float* pm          = (const float*)d_in[3];
    const float* wm          = (const float*)d_in[4];
    const float* outputs     = (const float*)d_in[5];
    float*       out         = (float*)d_out;

    const size_t transposed_bytes = (size_t)N_WORDS * VEC_D * sizeof(float);

    if (ws_size >= transposed_bytes) {
        float* outT = (float*)d_ws;
        transpose_kernel<<<N_WORDS / 32, 256, 0, stream>>>(outputs, outT);
        dm_kernel<true><<<BATCH / 16, 256, 0, stream>>>(
            doc_ids, context_ids, sample_ids, pm, wm, outT, out);
    } else {
        dm_kernel<false><<<BATCH / 16, 256, 0, stream>>>(
            doc_ids, context_ids, sample_ids, pm, wm, outputs, out);
    }
}